// Round 11
// baseline (265.165 us; speedup 1.0000x reference)
//
#include <hip/hip_runtime.h>

#define L_SEQ 1024
#define DMODEL 1024
#define LOG2E 1.4426950408889634f

typedef __attribute__((ext_vector_type(8))) short short8;
typedef __attribute__((ext_vector_type(4))) short shortx4;
typedef __attribute__((ext_vector_type(4))) float floatx4;

__device__ inline float bf2f(short s) {
    union { unsigned int u; float f; } v;
    v.u = ((unsigned int)(unsigned short)s) << 16;
    return v.f;
}
__device__ inline short f2bf(float f) {
    union { float f; unsigned int u; } v; v.f = f;
    unsigned int r = v.u + 0x7fff + ((v.u >> 16) & 1);
    return (short)(r >> 16);
}
__device__ inline void gload_lds16(const short* g, short* l) {
    __builtin_amdgcn_global_load_lds(
        (const __attribute__((address_space(1))) void*)g,
        (__attribute__((address_space(3))) void*)l, 16, 0, 0);
}

// ---------------- fused front-end: fp32->bf16 for x,Wq,Wk,Wv + proj ----------------
__global__ __launch_bounds__(256) void cvt_all(const float* __restrict__ x,
                                               const float* __restrict__ Wq,
                                               const float* __restrict__ Wk,
                                               const float* __restrict__ Wv,
                                               const float* __restrict__ ss,
                                               const float* __restrict__ ssw,
                                               short* __restrict__ xb,
                                               short* __restrict__ Wb,
                                               float* __restrict__ proj) {
    int bid = blockIdx.x;
    if (bid < 3584) {
        const float* src; short* dst; int off;
        if (bid < 2048)      { src = x;  dst = xb;               off = bid; }
        else if (bid < 2560) { src = Wq; dst = Wb;               off = bid - 2048; }
        else if (bid < 3072) { src = Wk; dst = Wb + (1u << 20);  off = bid - 2560; }
        else                 { src = Wv; dst = Wb + (2u << 20);  off = bid - 3072; }
        int idx = off * 256 + threadIdx.x;
        const float4* p = (const float4*)src + idx * 2;
        float4 a = p[0], b = p[1];
        short8 r;
        r[0] = f2bf(a.x); r[1] = f2bf(a.y); r[2] = f2bf(a.z); r[3] = f2bf(a.w);
        r[4] = f2bf(b.x); r[5] = f2bf(b.y); r[6] = f2bf(b.z); r[7] = f2bf(b.w);
        *(short8*)(dst + idx * 8) = r;
    } else {
        int idx = (bid - 3584) * 256 + threadIdx.x;
        int h = idx & 15;
        int bl = idx >> 4;
        float s = 0.f;
#pragma unroll
        for (int d = 0; d < 8; ++d)
            s += ss[bl * 8 + d] * ssw[h * 8 + d];
        proj[bl * 16 + h] = s;
    }
}

// ---------------- fused: 128x128 QKV GEMM blocks + bias blocks (block-routed) ----------------
// bid < 768: C = A(4096x1024).B(3072x1024)^T -> Q(scaled)/K/Vt
// bid >= 768: bias(xLOG2E) in MFMA-C tile order [b][ti][tj][(iq*16+jf)*4+ir]
__global__ __launch_bounds__(256) void gemm_qkv_bias(const short* __restrict__ xb,
                                                     const short* __restrict__ Wb,
                                                     short* __restrict__ Q,
                                                     short* __restrict__ K,
                                                     short* __restrict__ Vt,
                                                     const float* __restrict__ pf,
                                                     const int* __restrict__ ids,
                                                     const float* __restrict__ im,
                                                     const float* __restrict__ proj,
                                                     const float* __restrict__ ps,
                                                     const float* __restrict__ dd,
                                                     short* __restrict__ biasT) {
    __shared__ __align__(16) short As[128 * 32];
    __shared__ __align__(16) short Bs[128 * 32];
    __shared__ float pi[16][16];
    __shared__ float interrow[16][25];
    int bid = blockIdx.x;
    int t = threadIdx.x;
    if (bid < 768) {
        // ---- GEMM path ----
        int wave = t >> 6, lane = t & 63, fr = lane & 15, quad = lane >> 4;
        int wm = (wave & 1) * 64, wn = (wave >> 1) * 64;
        int m0 = (bid & 31) * 128, n0 = (bid >> 5) * 128;
        const short* Ag = xb + (m0 + (t >> 2)) * DMODEL + (t & 3) * 8;
        const short* Bg = Wb + (n0 + (t >> 2)) * DMODEL + (t & 3) * 8;
        short* Asd = As + t * 8;
        short* Bsd = Bs + t * 8;
        floatx4 acc[4][4] = {};
        for (int k0 = 0; k0 < DMODEL; k0 += 32) {
            __syncthreads();
            gload_lds16(Ag + k0, Asd);
            gload_lds16(Ag + 64 * DMODEL + k0, Asd + 2048);
            gload_lds16(Bg + k0, Bsd);
            gload_lds16(Bg + 64 * DMODEL + k0, Bsd + 2048);
            __syncthreads();
            short8 a[4], b[4];
#pragma unroll
            for (int i = 0; i < 4; ++i) {
                a[i] = *(const short8*)(As + (wm + i * 16 + fr) * 32 + quad * 8);
                b[i] = *(const short8*)(Bs + (wn + i * 16 + fr) * 32 + quad * 8);
            }
#pragma unroll
            for (int i = 0; i < 4; ++i)
#pragma unroll
                for (int j = 0; j < 4; ++j)
                    acc[i][j] = __builtin_amdgcn_mfma_f32_16x16x32_bf16(a[i], b[j], acc[i][j], 0, 0, 0);
        }
#pragma unroll
        for (int i = 0; i < 4; ++i)
#pragma unroll
            for (int j = 0; j < 4; ++j)
#pragma unroll
                for (int r = 0; r < 4; ++r) {
                    int m = m0 + wm + i * 16 + quad * 4 + r;
                    int n = n0 + wn + j * 16 + fr;
                    int b_ = m >> 10, ii = m & 1023;
                    int mode = n >> 10, nn = n & 1023;
                    int h = nn >> 6, d = nn & 63;
                    float v = acc[i][j][r];
                    if (mode == 0)
                        Q[((b_ * 16 + h) * L_SEQ + ii) * 64 + d] = f2bf(v * (0.125f * LOG2E));
                    else if (mode == 1)
                        K[((b_ * 16 + h) * L_SEQ + ii) * 64 + d] = f2bf(v);
                    else
                        Vt[((b_ * 16 + h) * 64 + d) * L_SEQ + ii] = f2bf(v);
                }
    } else {
        // ---- bias path ----
        int bid2 = bid - 768;           // 1024 blocks
        int ti = bid2 & 63;             // i-tile
        int jc = (bid2 >> 6) & 3;       // j-chunk (256 cols)
        int b  = bid2 >> 8;
        int iq = t >> 6, lane = t & 63;
        float decay = fminf(fmaxf(dd[0], 0.1f), 5.0f);
        float psig = 1.f / (1.f + __expf(-ps[0]));
        {
            int row = t >> 4, col = t & 15;
            pi[row][col] = proj[(((b << 10) + ti * 16 + row) << 4) + col];
            for (int e = t; e < 16 * 25; e += 256) {
                int il = e / 25, c = e - il * 25;
                int id_i = min(max(ids[(b << 10) + ti * 16 + il], 0), 24);
                interrow[il][c] = 0.5f * (im[id_i * 25 + c] + im[c * 25 + id_i]);
            }
        }
        __syncthreads();
        int j0 = jc * 256 + lane * 4;
        float4 pfv[4];
#pragma unroll
        for (int ir = 0; ir < 4; ++ir) {
            int i = ti * 16 + iq * 4 + ir;
            pfv[ir] = *(const float4*)(pf + (b << 20) + (i << 10) + j0);
        }
        int4 idj4 = *(const int4*)(ids + (b << 10) + j0);
        int idj[4] = {min(max(idj4.x, 0), 24), min(max(idj4.y, 0), 24),
                      min(max(idj4.z, 0), 24), min(max(idj4.w, 0), 24)};
        int tj = j0 >> 4, jf0 = j0 & 15;
        short* outp = biasT + ((((b << 6) + ti) << 6) + tj) * 256 + (iq * 16 + jf0) * 4;
#pragma unroll
        for (int e = 0; e < 4; ++e) {
            int j = j0 + e;
            const float4* pj4 = (const float4*)(proj + (((b << 10) + j) << 4));
            float4 p0 = pj4[0], p1 = pj4[1], p2 = pj4[2], p3 = pj4[3];
            shortx4 o;
#pragma unroll
            for (int ir = 0; ir < 4; ++ir) {
                int i = ti * 16 + iq * 4 + ir;
                float dvr = (e == 0) ? pfv[ir].x : (e == 1) ? pfv[ir].y : (e == 2) ? pfv[ir].z : pfv[ir].w;
                float dist = fminf(fmaxf(dvr, 0.1f), 50.0f);
                float dp = -__expf(decay * __logf(dist)) * psig;
                int il = iq * 4 + ir;
                float inter = interrow[il][idj[e]] / (1.0f + fabsf((float)(i - j)));
                const float* pir = pi[il];
                float dot = pir[0] * p0.x + pir[1] * p0.y + pir[2] * p0.z + pir[3] * p0.w
                          + pir[4] * p1.x + pir[5] * p1.y + pir[6] * p1.z + pir[7] * p1.w
                          + pir[8] * p2.x + pir[9] * p2.y + pir[10] * p2.z + pir[11] * p2.w
                          + pir[12] * p3.x + pir[13] * p3.y + pir[14] * p3.z + pir[15] * p3.w;
                float st = 1.f / (1.f + __expf(-dot)) - 0.5f;
                o[ir] = f2bf((dp + inter + st) * LOG2E);
            }
            *(shortx4*)(outp + e * 4) = o;
        }
    }
}

// ---------------- fp32 -> bf16 bulk convert (for Wo, after attn frees [0,8M)) ----------------
__global__ __launch_bounds__(256) void cvt_kernel(const float* __restrict__ src,
                                                  short* __restrict__ dst) {
    int idx = blockIdx.x * 256 + threadIdx.x;
    const float4* p = (const float4*)src + idx * 2;
    float4 a = p[0], b = p[1];
    short8 r;
    r[0] = f2bf(a.x); r[1] = f2bf(a.y); r[2] = f2bf(a.z); r[3] = f2bf(a.w);
    r[4] = f2bf(b.x); r[5] = f2bf(b.y); r[6] = f2bf(b.z); r[7] = f2bf(b.w);
    *(short8*)(dst + idx * 8) = r;
}

// ---------------- m97-style 128x128 GEMM: out = ctx(4096x1024) . Wo(1024x1024)^T + bo ----------------
__global__ __launch_bounds__(256) void gemm_out(const short* __restrict__ ctx,
                                                const short* __restrict__ Wob,
                                                const float* __restrict__ bo,
                                                float* __restrict__ out) {
    __shared__ __align__(16) short As[128 * 32];
    __shared__ __align__(16) short Bs[128 * 32];
    int t = threadIdx.x;
    int wave = t >> 6, lane = t & 63, fr = lane & 15, quad = lane >> 4;
    int wm = (wave & 1) * 64, wn = (wave >> 1) * 64;
    int m0 = blockIdx.x * 128, n0 = blockIdx.y * 128;
    const short* Ag = ctx + (m0 + (t >> 2)) * DMODEL + (t & 3) * 8;
    const short* Bg = Wob + (n0 + (t >> 2)) * DMODEL + (t & 3) * 8;
    short* Asd = As + t * 8;
    short* Bsd = Bs + t * 8;
    floatx4 acc[4][4] = {};
    for (int k0 = 0; k0 < DMODEL; k0 += 32) {
        __syncthreads();
        gload_lds16(Ag + k0, Asd);
        gload_lds16(Ag + 64 * DMODEL + k0, Asd + 2048);
        gload_lds16(Bg + k0, Bsd);
        gload_lds16(Bg + 64 * DMODEL + k0, Bsd + 2048);
        __syncthreads();
        short8 a[4], b[4];
#pragma unroll
        for (int i = 0; i < 4; ++i) {
            a[i] = *(const short8*)(As + (wm + i * 16 + fr) * 32 + quad * 8);
            b[i] = *(const short8*)(Bs + (wn + i * 16 + fr) * 32 + quad * 8);
        }
#pragma unroll
        for (int i = 0; i < 4; ++i)
#pragma unroll
            for (int j = 0; j < 4; ++j)
                acc[i][j] = __builtin_amdgcn_mfma_f32_16x16x32_bf16(a[i], b[j], acc[i][j], 0, 0, 0);
    }
#pragma unroll
    for (int i = 0; i < 4; ++i)
#pragma unroll
        for (int j = 0; j < 4; ++j)
#pragma unroll
            for (int r = 0; r < 4; ++r) {
                int m = m0 + wm + i * 16 + quad * 4 + r;
                int n = n0 + wn + j * 16 + fr;
                out[m * DMODEL + n] = acc[i][j][r] + bo[n];
            }
}

// ---------------- flash attention v2 (best measured): 2 i-tiles/wave, 128 rows/block,
// exp2 max-free softmax (log2e pre-folded into Q and bias), double-buffered K/V ----------------
#define KSTR 72
#define VSTR 136
#define PSTR 136
__global__ __launch_bounds__(256, 2) void attn_kernel(const short* __restrict__ Q,
                                                      const short* __restrict__ K,
                                                      const short* __restrict__ Vt,
                                                      const short* __restrict__ biasT,
                                                      short* __restrict__ ctx) {
    __shared__ __align__(16) short Ks[128 * KSTR];          // 18432 B
    __shared__ __align__(16) short Vs[64 * VSTR];           // 17408 B
    __shared__ __align__(16) short Ps[4 * 2 * 16 * PSTR];   // 34816 B
    int bh = blockIdx.x;            // b*16+h
    int b = bh >> 4, h = bh & 15;
    int i0 = blockIdx.y * 128;
    int t = threadIdx.x;
    int w = t >> 6, lane = t & 63, fr = lane & 15, quad = lane >> 4;
    const short* Kg = K + (bh << 16);
    const short* Vg = Vt + (bh << 16);
    short* myP = Ps + w * (2 * 16 * PSTR);
    int tib[2];
    tib[0] = (((b << 6) + (i0 >> 4) + w * 2) << 6);
    tib[1] = tib[0] + 64;

    short8 qf[2][2];
#pragma unroll
    for (int it = 0; it < 2; ++it) {
        const short8* qp = (const short8*)(Q + ((bh << 10) + i0 + w * 32 + it * 16 + fr) * 64 + quad * 8);
        qf[it][0] = qp[0];
        qf[it][1] = qp[4];
    }
    float psum[2][4] = {};
    floatx4 pv[2][4] = {};

    short8 kreg[4], vreg[4];
#pragma unroll
    for (int s = 0; s < 4; ++s) {
        int seg = s * 256 + t;
        kreg[s] = *(const short8*)(Kg + (seg >> 3) * 64 + (seg & 7) * 8);
        vreg[s] = *(const short8*)(Vg + (seg >> 4) * 1024 + (seg & 15) * 8);
    }

    for (int jc = 0; jc < 8; ++jc) {
        if (jc) __syncthreads();
#pragma unroll
        for (int s = 0; s < 4; ++s) {
            int seg = s * 256 + t;
            *(short8*)(Ks + (seg >> 3) * KSTR + (seg & 7) * 8) = kreg[s];
            *(short8*)(Vs + (seg >> 4) * VSTR + (seg & 15) * 8) = vreg[s];
        }
        __syncthreads();
        if (jc < 7) {
#pragma unroll
            for (int s = 0; s < 4; ++s) {
                int seg = s * 256 + t;
                kreg[s] = *(const short8*)(Kg + ((jc + 1) * 128 + (seg >> 3)) * 64 + (seg & 7) * 8);
                vreg[s] = *(const short8*)(Vg + (seg >> 4) * 1024 + (jc + 1) * 128 + (seg & 15) * 8);
            }
        }
        shortx4 bfv[2][8];
#pragma unroll
        for (int it = 0; it < 2; ++it)
#pragma unroll
            for (int jt = 0; jt < 8; ++jt)
                bfv[it][jt] = *(const shortx4*)(biasT + ((tib[it] + jc * 8 + jt) << 8) + lane * 4);
        floatx4 sc[2][8];
#pragma unroll
        for (int jt = 0; jt < 8; ++jt) {
            short8 kb0 = *(const short8*)(Ks + (jt * 16 + fr) * KSTR + quad * 8);
            short8 kb1 = *(const short8*)(Ks + (jt * 16 + fr) * KSTR + 32 + quad * 8);
#pragma unroll
            for (int it = 0; it < 2; ++it) {
                floatx4 a = {0.f, 0.f, 0.f, 0.f};
                a = __builtin_amdgcn_mfma_f32_16x16x32_bf16(qf[it][0], kb0, a, 0, 0, 0);
                a = __builtin_amdgcn_mfma_f32_16x16x32_bf16(qf[it][1], kb1, a, 0, 0, 0);
                sc[it][jt] = a;
            }
        }
#pragma unroll
        for (int it = 0; it < 2; ++it)
#pragma unroll
            for (int jt = 0; jt < 8; ++jt)
#pragma unroll
                for (int r = 0; r < 4; ++r) {
                    float e = exp2f(sc[it][jt][r] + bf2f(bfv[it][jt][r]));
                    psum[it][r] += e;
                    myP[(it * 16 + quad * 4 + r) * PSTR + jt * 16 + fr] = f2bf(e);
                }
#pragma unroll
        for (int ks = 0; ks < 4; ++ks) {
            short8 pa[2], vb[4];
#pragma unroll
            for (int it = 0; it < 2; ++it)
                pa[it] = *(const short8*)(myP + (it * 16 + fr) * PSTR + ks * 32 + quad * 8);
#pragma unroll
            for (int dt = 0; dt < 4; ++dt)
                vb[dt] = *(const short8*)(Vs + (dt * 16 + fr) * VSTR + ks * 32 + quad * 8);
#pragma unroll
            for (int it = 0; it < 2; ++it)
#pragma unroll
                for (int dt = 0; dt < 4; ++dt)
                    pv[it][dt] = __builtin_amdgcn_mfma_f32_16x16x32_bf16(pa[it], vb[dt], pv[it][dt], 0, 0, 0);
        }
    }
#pragma unroll
    for (int it = 0; it < 2; ++it)
#pragma unroll
        for (int r = 0; r < 4; ++r) {
#pragma unroll
            for (int mask = 8; mask >= 1; mask >>= 1)
                psum[it][r] += __shfl_xor(psum[it][r], mask);
            psum[it][r] = 1.f / psum[it][r];
        }
#pragma unroll
    for (int it = 0; it < 2; ++it)
#pragma unroll
        for (int dt = 0; dt < 4; ++dt)
#pragma unroll
            for (int r = 0; r < 4; ++r) {
                int i = i0 + w * 32 + it * 16 + quad * 4 + r;
                ctx[((b << 10) + i) * DMODEL + h * 64 + dt * 16 + fr] = f2bf(pv[it][dt][r] * psum[it][r]);
            }
}

extern "C" void kernel_launch(void* const* d_in, const int* in_sizes, int n_in,
                              void* d_out, int out_size, void* d_ws, size_t ws_size,
                              hipStream_t stream) {
    const float* x   = (const float*)d_in[0];
    const float* pf  = (const float*)d_in[1];
    const int*   ids = (const int*)d_in[2];
    const float* ss  = (const float*)d_in[3];
    const float* Wq  = (const float*)d_in[4];
    const float* Wk  = (const float*)d_in[5];
    const float* Wv  = (const float*)d_in[6];
    const float* Wo  = (const float*)d_in[7];
    const float* bo  = (const float*)d_in[8];
    const float* im  = (const float*)d_in[10];
    const float* ssw = (const float*)d_in[11];
    const float* ps  = (const float*)d_in[12];
    const float* dd  = (const float*)d_in[13];
    float* out = (float*)d_out;

    // ws plan (40 MB), overlays strictly stream-ordered:
    //  [0,8M):   xb (until gemm) -> biasT (bias..attn) -> Wob (cvt after attn)
    //  [8,16M):  Q   [16,24M): K   [24,32M): Vt
    //  [32,38M): Wb (until gemm) -> ctx [32,40M) (attn..gemm_out)
    //  [38,38.25M): proj (until bias path done; overwritten later by ctx)
    char* ws = (char*)d_ws;
    short* xb    = (short*)(ws);
    short* biasT = (short*)(ws);
    short* Wob   = (short*)(ws);
    short* Q     = (short*)(ws + (8u  << 20));
    short* K     = (short*)(ws + (16u << 20));
    short* Vt    = (short*)(ws + (24u << 20));
    short* Wb    = (short*)(ws + (32u << 20));
    short* ctx   = (short*)(ws + (32u << 20));
    float* proj  = (float*)(ws + (38u << 20));

    hipLaunchKernelGGL(cvt_all, dim3(3840), dim3(256), 0, stream,
                       x, Wq, Wk, Wv, ss, ssw, xb, Wb, proj);
    hipLaunchKernelGGL(gemm_qkv_bias, dim3(1792), dim3(256), 0, stream,
                       xb, Wb, Q, K, Vt, pf, ids, im, proj, ps, dd, biasT);
    hipLaunchKernelGGL(attn_kernel, dim3(64, 8), dim3(256), 0, stream,
                       Q, K, Vt, biasT, ctx);
    hipLaunchKernelGGL(cvt_kernel, dim3(512), dim3(256), 0, stream, Wo, Wob);
    hipLaunchKernelGGL(gemm_out, dim3(32, 8), dim3(256), 0, stream, ctx, Wob, bo, out);
}

// Round 12
// 233.530 us; speedup vs baseline: 1.1355x; 1.1355x over previous
//
#include <hip/hip_runtime.h>

#define L_SEQ 1024
#define DMODEL 1024
#define LOG2E 1.4426950408889634f

typedef __attribute__((ext_vector_type(8))) short short8;
typedef __attribute__((ext_vector_type(4))) short shortx4;
typedef __attribute__((ext_vector_type(4))) float floatx4;

__device__ inline float bf2f(short s) {
    union { unsigned int u; float f; } v;
    v.u = ((unsigned int)(unsigned short)s) << 16;
    return v.f;
}
__device__ inline short f2bf(float f) {
    union { float f; unsigned int u; } v; v.f = f;
    unsigned int r = v.u + 0x7fff + ((v.u >> 16) & 1);
    return (short)(r >> 16);
}
__device__ inline void gload_lds16(const short* g, short* l) {
    __builtin_amdgcn_global_load_lds(
        (const __attribute__((address_space(1))) void*)g,
        (__attribute__((address_space(3))) void*)l, 16, 0, 0);
}

// ---------------- fused front-end: fp32->bf16 for x,Wq,Wk,Wv + proj ----------------
__global__ __launch_bounds__(256) void cvt_all(const float* __restrict__ x,
                                               const float* __restrict__ Wq,
                                               const float* __restrict__ Wk,
                                               const float* __restrict__ Wv,
                                               const float* __restrict__ ss,
                                               const float* __restrict__ ssw,
                                               short* __restrict__ xb,
                                               short* __restrict__ Wb,
                                               float* __restrict__ proj) {
    int bid = blockIdx.x;
    if (bid < 3584) {
        const float* src; short* dst; int off;
        if (bid < 2048)      { src = x;  dst = xb;               off = bid; }
        else if (bid < 2560) { src = Wq; dst = Wb;               off = bid - 2048; }
        else if (bid < 3072) { src = Wk; dst = Wb + (1u << 20);  off = bid - 2560; }
        else                 { src = Wv; dst = Wb + (2u << 20);  off = bid - 3072; }
        int idx = off * 256 + threadIdx.x;
        const float4* p = (const float4*)src + idx * 2;
        float4 a = p[0], b = p[1];
        short8 r;
        r[0] = f2bf(a.x); r[1] = f2bf(a.y); r[2] = f2bf(a.z); r[3] = f2bf(a.w);
        r[4] = f2bf(b.x); r[5] = f2bf(b.y); r[6] = f2bf(b.z); r[7] = f2bf(b.w);
        *(short8*)(dst + idx * 8) = r;
    } else {
        int idx = (bid - 3584) * 256 + threadIdx.x;
        int h = idx & 15;
        int bl = idx >> 4;
        float s = 0.f;
#pragma unroll
        for (int d = 0; d < 8; ++d)
            s += ss[bl * 8 + d] * ssw[h * 8 + d];
        proj[bl * 16 + h] = s;
    }
}

// ---------------- bias (xLOG2E) in MFMA-C tile order: [b][ti][tj][(iq*16+jf)*4 + ir] ----------------
__global__ __launch_bounds__(256) void bias_kernel(const float* __restrict__ pf,
                                                   const int* __restrict__ ids,
                                                   const float* __restrict__ im,
                                                   const float* __restrict__ proj,
                                                   const float* __restrict__ ps,
                                                   const float* __restrict__ dd,
                                                   short* __restrict__ biasT) {
    int ti = blockIdx.x;
    int jc = blockIdx.y;
    int b  = blockIdx.z;
    int t = threadIdx.x;
    int iq = t >> 6, lane = t & 63;
    float decay = fminf(fmaxf(dd[0], 0.1f), 5.0f);
    float psig = 1.f / (1.f + __expf(-ps[0]));

    __shared__ float pi[16][16];
    __shared__ float interrow[16][25];
    {
        int row = t >> 4, col = t & 15;
        pi[row][col] = proj[(((b << 10) + ti * 16 + row) << 4) + col];
        for (int e = t; e < 16 * 25; e += 256) {
            int il = e / 25, c = e - il * 25;
            int id_i = min(max(ids[(b << 10) + ti * 16 + il], 0), 24);
            interrow[il][c] = 0.5f * (im[id_i * 25 + c] + im[c * 25 + id_i]);
        }
    }
    __syncthreads();

    int j0 = jc * 256 + lane * 4;
    float4 pfv[4];
#pragma unroll
    for (int ir = 0; ir < 4; ++ir) {
        int i = ti * 16 + iq * 4 + ir;
        pfv[ir] = *(const float4*)(pf + (b << 20) + (i << 10) + j0);
    }
    int4 idj4 = *(const int4*)(ids + (b << 10) + j0);
    int idj[4] = {min(max(idj4.x, 0), 24), min(max(idj4.y, 0), 24),
                  min(max(idj4.z, 0), 24), min(max(idj4.w, 0), 24)};

    int tj = j0 >> 4, jf0 = j0 & 15;
    short* outp = biasT + ((((b << 6) + ti) << 6) + tj) * 256 + (iq * 16 + jf0) * 4;
#pragma unroll
    for (int e = 0; e < 4; ++e) {
        int j = j0 + e;
        const float4* pj4 = (const float4*)(proj + (((b << 10) + j) << 4));
        float4 p0 = pj4[0], p1 = pj4[1], p2 = pj4[2], p3 = pj4[3];
        shortx4 o;
#pragma unroll
        for (int ir = 0; ir < 4; ++ir) {
            int i = ti * 16 + iq * 4 + ir;
            float dvr = (e == 0) ? pfv[ir].x : (e == 1) ? pfv[ir].y : (e == 2) ? pfv[ir].z : pfv[ir].w;
            float dist = fminf(fmaxf(dvr, 0.1f), 50.0f);
            float dp = -__expf(decay * __logf(dist)) * psig;
            int il = iq * 4 + ir;
            float inter = interrow[il][idj[e]] / (1.0f + fabsf((float)(i - j)));
            const float* pir = pi[il];
            float dot = pir[0] * p0.x + pir[1] * p0.y + pir[2] * p0.z + pir[3] * p0.w
                      + pir[4] * p1.x + pir[5] * p1.y + pir[6] * p1.z + pir[7] * p1.w
                      + pir[8] * p2.x + pir[9] * p2.y + pir[10] * p2.z + pir[11] * p2.w
                      + pir[12] * p3.x + pir[13] * p3.y + pir[14] * p3.z + pir[15] * p3.w;
            float st = 1.f / (1.f + __expf(-dot)) - 0.5f;
            o[ir] = f2bf((dp + inter + st) * LOG2E);   // pre-scaled for exp2 softmax
        }
        *(shortx4*)(outp + e * 4) = o;
    }
}

// ---------------- m97-style 128x128 GEMM: C = A(4096x1024) . B(3072x1024)^T ----------------
__global__ __launch_bounds__(256) void gemm_qkv(const short* __restrict__ xb,
                                                const short* __restrict__ Wb,
                                                short* __restrict__ Q,
                                                short* __restrict__ K,
                                                short* __restrict__ Vt) {
    __shared__ __align__(16) short As[128 * 32];
    __shared__ __align__(16) short Bs[128 * 32];
    int t = threadIdx.x;
    int wave = t >> 6, lane = t & 63, fr = lane & 15, quad = lane >> 4;
    int wm = (wave & 1) * 64, wn = (wave >> 1) * 64;
    int m0 = blockIdx.x * 128, n0 = blockIdx.y * 128;
    const short* Ag = xb + (m0 + (t >> 2)) * DMODEL + (t & 3) * 8;
    const short* Bg = Wb + (n0 + (t >> 2)) * DMODEL + (t & 3) * 8;
    short* Asd = As + t * 8;
    short* Bsd = Bs + t * 8;
    floatx4 acc[4][4] = {};
    for (int k0 = 0; k0 < DMODEL; k0 += 32) {
        __syncthreads();
        gload_lds16(Ag + k0, Asd);
        gload_lds16(Ag + 64 * DMODEL + k0, Asd + 2048);
        gload_lds16(Bg + k0, Bsd);
        gload_lds16(Bg + 64 * DMODEL + k0, Bsd + 2048);
        __syncthreads();
        short8 a[4], b[4];
#pragma unroll
        for (int i = 0; i < 4; ++i) {
            a[i] = *(const short8*)(As + (wm + i * 16 + fr) * 32 + quad * 8);
            b[i] = *(const short8*)(Bs + (wn + i * 16 + fr) * 32 + quad * 8);
        }
#pragma unroll
        for (int i = 0; i < 4; ++i)
#pragma unroll
            for (int j = 0; j < 4; ++j)
                acc[i][j] = __builtin_amdgcn_mfma_f32_16x16x32_bf16(a[i], b[j], acc[i][j], 0, 0, 0);
    }
#pragma unroll
    for (int i = 0; i < 4; ++i)
#pragma unroll
        for (int j = 0; j < 4; ++j)
#pragma unroll
            for (int r = 0; r < 4; ++r) {
                int m = m0 + wm + i * 16 + quad * 4 + r;
                int n = n0 + wn + j * 16 + fr;
                int b_ = m >> 10, ii = m & 1023;
                int mode = n >> 10, nn = n & 1023;
                int h = nn >> 6, d = nn & 63;
                float v = acc[i][j][r];
                if (mode == 0)
                    Q[((b_ * 16 + h) * L_SEQ + ii) * 64 + d] = f2bf(v * (0.125f * LOG2E));
                else if (mode == 1)
                    K[((b_ * 16 + h) * L_SEQ + ii) * 64 + d] = f2bf(v);
                else
                    Vt[((b_ * 16 + h) * 64 + d) * L_SEQ + ii] = f2bf(v);
            }
}

// ---------------- fp32 -> bf16 bulk convert (for Wo, after attn frees [0,8M)) ----------------
__global__ __launch_bounds__(256) void cvt_kernel(const float* __restrict__ src,
                                                  short* __restrict__ dst) {
    int idx = blockIdx.x * 256 + threadIdx.x;
    const float4* p = (const float4*)src + idx * 2;
    float4 a = p[0], b = p[1];
    short8 r;
    r[0] = f2bf(a.x); r[1] = f2bf(a.y); r[2] = f2bf(a.z); r[3] = f2bf(a.w);
    r[4] = f2bf(b.x); r[5] = f2bf(b.y); r[6] = f2bf(b.z); r[7] = f2bf(b.w);
    *(short8*)(dst + idx * 8) = r;
}

// ---------------- m97-style 128x128 GEMM: out = ctx(4096x1024) . Wo(1024x1024)^T + bo ----------------
__global__ __launch_bounds__(256) void gemm_out(const short* __restrict__ ctx,
                                                const short* __restrict__ Wob,
                                                const float* __restrict__ bo,
                                                float* __restrict__ out) {
    __shared__ __align__(16) short As[128 * 32];
    __shared__ __align__(16) short Bs[128 * 32];
    int t = threadIdx.x;
    int wave = t >> 6, lane = t & 63, fr = lane & 15, quad = lane >> 4;
    int wm = (wave & 1) * 64, wn = (wave >> 1) * 64;
    int m0 = blockIdx.x * 128, n0 = blockIdx.y * 128;
    const short* Ag = ctx + (m0 + (t >> 2)) * DMODEL + (t & 3) * 8;
    const short* Bg = Wob + (n0 + (t >> 2)) * DMODEL + (t & 3) * 8;
    short* Asd = As + t * 8;
    short* Bsd = Bs + t * 8;
    floatx4 acc[4][4] = {};
    for (int k0 = 0; k0 < DMODEL; k0 += 32) {
        __syncthreads();
        gload_lds16(Ag + k0, Asd);
        gload_lds16(Ag + 64 * DMODEL + k0, Asd + 2048);
        gload_lds16(Bg + k0, Bsd);
        gload_lds16(Bg + 64 * DMODEL + k0, Bsd + 2048);
        __syncthreads();
        short8 a[4], b[4];
#pragma unroll
        for (int i = 0; i < 4; ++i) {
            a[i] = *(const short8*)(As + (wm + i * 16 + fr) * 32 + quad * 8);
            b[i] = *(const short8*)(Bs + (wn + i * 16 + fr) * 32 + quad * 8);
        }
#pragma unroll
        for (int i = 0; i < 4; ++i)
#pragma unroll
            for (int j = 0; j < 4; ++j)
                acc[i][j] = __builtin_amdgcn_mfma_f32_16x16x32_bf16(a[i], b[j], acc[i][j], 0, 0, 0);
    }
#pragma unroll
    for (int i = 0; i < 4; ++i)
#pragma unroll
        for (int j = 0; j < 4; ++j)
#pragma unroll
            for (int r = 0; r < 4; ++r) {
                int m = m0 + wm + i * 16 + quad * 4 + r;
                int n = n0 + wn + j * 16 + fr;
                out[m * DMODEL + n] = acc[i][j][r] + bo[n];
            }
}

// ---------------- flash attention v2 (best measured): 2 i-tiles/wave, 128 rows/block,
// exp2 max-free softmax (log2e pre-folded into Q and bias), double-buffered K/V ----------------
#define KSTR 72
#define VSTR 136
#define PSTR 136
__global__ __launch_bounds__(256, 2) void attn_kernel(const short* __restrict__ Q,
                                                      const short* __restrict__ K,
                                                      const short* __restrict__ Vt,
                                                      const short* __restrict__ biasT,
                                                      short* __restrict__ ctx) {
    __shared__ __align__(16) short Ks[128 * KSTR];          // 18432 B
    __shared__ __align__(16) short Vs[64 * VSTR];           // 17408 B
    __shared__ __align__(16) short Ps[4 * 2 * 16 * PSTR];   // 34816 B
    int bh = blockIdx.x;            // b*16+h
    int b = bh >> 4, h = bh & 15;
    int i0 = blockIdx.y * 128;
    int t = threadIdx.x;
    int w = t >> 6, lane = t & 63, fr = lane & 15, quad = lane >> 4;
    const short* Kg = K + (bh << 16);
    const short* Vg = Vt + (bh << 16);
    short* myP = Ps + w * (2 * 16 * PSTR);
    int tib[2];
    tib[0] = (((b << 6) + (i0 >> 4) + w * 2) << 6);
    tib[1] = tib[0] + 64;

    short8 qf[2][2];
#pragma unroll
    for (int it = 0; it < 2; ++it) {
        const short8* qp = (const short8*)(Q + ((bh << 10) + i0 + w * 32 + it * 16 + fr) * 64 + quad * 8);
        qf[it][0] = qp[0];
        qf[it][1] = qp[4];
    }
    float psum[2][4] = {};
    floatx4 pv[2][4] = {};

    short8 kreg[4], vreg[4];
#pragma unroll
    for (int s = 0; s < 4; ++s) {
        int seg = s * 256 + t;
        kreg[s] = *(const short8*)(Kg + (seg >> 3) * 64 + (seg & 7) * 8);
        vreg[s] = *(const short8*)(Vg + (seg >> 4) * 1024 + (seg & 15) * 8);
    }

    for (int jc = 0; jc < 8; ++jc) {
        if (jc) __syncthreads();
#pragma unroll
        for (int s = 0; s < 4; ++s) {
            int seg = s * 256 + t;
            *(short8*)(Ks + (seg >> 3) * KSTR + (seg & 7) * 8) = kreg[s];
            *(short8*)(Vs + (seg >> 4) * VSTR + (seg & 15) * 8) = vreg[s];
        }
        __syncthreads();
        if (jc < 7) {
#pragma unroll
            for (int s = 0; s < 4; ++s) {
                int seg = s * 256 + t;
                kreg[s] = *(const short8*)(Kg + ((jc + 1) * 128 + (seg >> 3)) * 64 + (seg & 7) * 8);
                vreg[s] = *(const short8*)(Vg + (seg >> 4) * 1024 + (jc + 1) * 128 + (seg & 15) * 8);
            }
        }
        shortx4 bfv[2][8];
#pragma unroll
        for (int it = 0; it < 2; ++it)
#pragma unroll
            for (int jt = 0; jt < 8; ++jt)
                bfv[it][jt] = *(const shortx4*)(biasT + ((tib[it] + jc * 8 + jt) << 8) + lane * 4);
        floatx4 sc[2][8];
#pragma unroll
        for (int jt = 0; jt < 8; ++jt) {
            short8 kb0 = *(const short8*)(Ks + (jt * 16 + fr) * KSTR + quad * 8);
            short8 kb1 = *(const short8*)(Ks + (jt * 16 + fr) * KSTR + 32 + quad * 8);
#pragma unroll
            for (int it = 0; it < 2; ++it) {
                floatx4 a = {0.f, 0.f, 0.f, 0.f};
                a = __builtin_amdgcn_mfma_f32_16x16x32_bf16(qf[it][0], kb0, a, 0, 0, 0);
                a = __builtin_amdgcn_mfma_f32_16x16x32_bf16(qf[it][1], kb1, a, 0, 0, 0);
                sc[it][jt] = a;
            }
        }
#pragma unroll
        for (int it = 0; it < 2; ++it)
#pragma unroll
            for (int jt = 0; jt < 8; ++jt)
#pragma unroll
                for (int r = 0; r < 4; ++r) {
                    float e = exp2f(sc[it][jt][r] + bf2f(bfv[it][jt][r]));
                    psum[it][r] += e;
                    myP[(it * 16 + quad * 4 + r) * PSTR + jt * 16 + fr] = f2bf(e);
                }
#pragma unroll
        for (int ks = 0; ks < 4; ++ks) {
            short8 pa[2], vb[4];
#pragma unroll
            for (int it = 0; it < 2; ++it)
                pa[it] = *(const short8*)(myP + (it * 16 + fr) * PSTR + ks * 32 + quad * 8);
#pragma unroll
            for (int dt = 0; dt < 4; ++dt)
                vb[dt] = *(const short8*)(Vs + (dt * 16 + fr) * VSTR + ks * 32 + quad * 8);
#pragma unroll
            for (int it = 0; it < 2; ++it)
#pragma unroll
                for (int dt = 0; dt < 4; ++dt)
                    pv[it][dt] = __builtin_amdgcn_mfma_f32_16x16x32_bf16(pa[it], vb[dt], pv[it][dt], 0, 0, 0);
        }
    }
#pragma unroll
    for (int it = 0; it < 2; ++it)
#pragma unroll
        for (int r = 0; r < 4; ++r) {
#pragma unroll
            for (int mask = 8; mask >= 1; mask >>= 1)
                psum[it][r] += __shfl_xor(psum[it][r], mask);
            psum[it][r] = 1.f / psum[it][r];
        }
#pragma unroll
    for (int it = 0; it < 2; ++it)
#pragma unroll
        for (int dt = 0; dt < 4; ++dt)
#pragma unroll
            for (int r = 0; r < 4; ++r) {
                int i = i0 + w * 32 + it * 16 + quad * 4 + r;
                ctx[((b << 10) + i) * DMODEL + h * 64 + dt * 16 + fr] = f2bf(pv[it][dt][r] * psum[it][r]);
            }
}

extern "C" void kernel_launch(void* const* d_in, const int* in_sizes, int n_in,
                              void* d_out, int out_size, void* d_ws, size_t ws_size,
                              hipStream_t stream) {
    const float* x   = (const float*)d_in[0];
    const float* pf  = (const float*)d_in[1];
    const int*   ids = (const int*)d_in[2];
    const float* ss  = (const float*)d_in[3];
    const float* Wq  = (const float*)d_in[4];
    const float* Wk  = (const float*)d_in[5];
    const float* Wv  = (const float*)d_in[6];
    const float* Wo  = (const float*)d_in[7];
    const float* bo  = (const float*)d_in[8];
    const float* im  = (const float*)d_in[10];
    const float* ssw = (const float*)d_in[11];
    const float* ps  = (const float*)d_in[12];
    const float* dd  = (const float*)d_in[13];
    float* out = (float*)d_out;

    // ws plan (40 MB), overlays strictly stream-ordered:
    //  [0,8M):   xb (until gemm_qkv) -> biasT (bias..attn) -> Wob (cvt after attn)
    //  [8,16M):  Q   [16,24M): K   [24,32M): Vt
    //  [32,38M): Wb (until gemm_qkv) -> ctx [32,40M) (attn..gemm_out)
    //  [38,38.25M): proj (until bias_kernel; overwritten later by ctx)
    char* ws = (char*)d_ws;
    short* xb    = (short*)(ws);
    short* biasT = (short*)(ws);
    short* Wob   = (short*)(ws);
    short* Q     = (short*)(ws + (8u  << 20));
    short* K     = (short*)(ws + (16u << 20));
    short* Vt    = (short*)(ws + (24u << 20));
    short* Wb    = (short*)(ws + (32u << 20));
    short* ctx   = (short*)(ws + (32u << 20));
    float* proj  = (float*)(ws + (38u << 20));

    hipLaunchKernelGGL(cvt_all, dim3(3840), dim3(256), 0, stream,
                       x, Wq, Wk, Wv, ss, ssw, xb, Wb, proj);
    hipLaunchKernelGGL(gemm_qkv, dim3(32, 24), dim3(256), 0, stream, xb, Wb, Q, K, Vt);
    hipLaunchKernelGGL(bias_kernel, dim3(64, 4, 4), dim3(256), 0, stream,
                       pf, ids, im, proj, ps, dd, biasT);
    hipLaunchKernelGGL(attn_kernel, dim3(64, 8), dim3(256), 0, stream,
                       Q, K, Vt, biasT, ctx);
    hipLaunchKernelGGL(cvt_kernel, dim3(512), dim3(256), 0, stream, Wo, Wob);
    hipLaunchKernelGGL(gemm_out, dim3(32, 8), dim3(256), 0, stream, ctx, Wob, bo, out);
}